// Round 8
// baseline (261.941 us; speedup 1.0000x reference)
//
#include <hip/hip_runtime.h>

// Grouped int32 GEMM, scaled, f32 out.
// A flat: per group [k, M] (k-major). B flat: per group [k, N].
// O[g][m][n] = (sum_k A[k][m]*B[k][n]) * scale[g][n] * pts[g][m]
//
// Round 8: i8 MFMA (values 0..127 exact in int8; i32 accum exact;
// sums < 2^24 so f32 convert exact) enables a FULL-WIDTH B panel in LDS
// (2048 x 64 i8 = 128 KB). Each block computes 128 complete output rows
// -> writes one CONTIGUOUS 1 MB chunk of d_out (the fill kernel's
// footprint property). Theory: HBM write order = L2 eviction order, so
// per-block footprint contiguity (not per-instruction segment size) is
// what determines DRAM page locality. 256 blocks, 1/CU, XCD-chunked.

#define M_ 2048
#define N_ 2048
#define G_ 16

typedef __attribute__((ext_vector_type(4))) int   i32x4;
typedef __attribute__((ext_vector_type(4))) float f32x4;

// 16B-slot XOR swizzle within a 64B LDS row (same involution on write+read).
__device__ __forceinline__ int slot_swz(int row, int slot) {
    return slot ^ ((row >> 1) & 3);
}

__global__ __launch_bounds__(256, 1)
void grouped_gemm_kernel(const int* __restrict__ a,
                         const int* __restrict__ b,
                         const float* __restrict__ scale,
                         const float* __restrict__ pts,
                         const int* __restrict__ gl,
                         float* __restrict__ out)
{
    // 128 KB + 8 KB + 8 KB = 144 KB (<= 160 KB/CU)
    __shared__ __align__(16) unsigned char Bs[2048 * 64]; // [n][k] i8, swizzled
    __shared__ __align__(16) unsigned char As[128 * 64];  // [m][k] i8, swizzled
    __shared__ __align__(16) float         ScL[2048];     // scale row

    const int tid = threadIdx.x;
    // XCD-chunked swizzle (bijective: 256 = 8*32): XCD x gets 32 consecutive
    // virtual blocks = 2 whole groups -> inputs stay L2-resident per XCD.
    const int bx0 = blockIdx.x;
    const int bx  = (bx0 & 7) * 32 + (bx0 >> 3);
    const int ind = bx >> 4;            // group
    const int m0  = (bx & 15) * 128;    // m-chunk: 128 full rows

    const int prefix = (ind == 0) ? 0 : gl[ind - 1];
    const int kg     = gl[ind] - prefix;

    float* outg = out + (size_t)ind * ((size_t)M_ * N_);

    if (kg <= 0) {
        // empty group: zero-fill this block's contiguous 1 MB chunk
        float* o = outg + (size_t)m0 * N_;
        f32x4 z = {0.f, 0.f, 0.f, 0.f};
        #pragma unroll 4
        for (int i = 0; i < 256; ++i) {
            int idx = i * 256 + tid;
            *(f32x4*)(o + (size_t)idx * 4) = z;
        }
        return;
    }

    const int* ag = a + (size_t)prefix * M_;
    const int* bg = b + (size_t)prefix * N_;

    // ---- stage B panel [2048 n][64 k] i8, zero-padded in k ----
    // int1 loads keep LDS writes lane-row-consecutive (stride 64B -> 2-way).
    #pragma unroll 1
    for (int oct = 0; oct < 8; ++oct) {
        const int k0 = oct * 8;
        const int so = slot_swz(0, oct >> 1);   // placeholder; real swz per n
        (void)so;
        #pragma unroll 1
        for (int nb = 0; nb < 8; ++nb) {
            const int n = nb * 256 + tid;
            unsigned long long v = 0ull;
            if (k0 < kg) {
                #pragma unroll
                for (int j = 0; j < 8; ++j) {
                    const int k = k0 + j;
                    unsigned byte = (k < kg) ? ((unsigned)bg[k * N_ + n] & 0xFFu) : 0u;
                    v |= (unsigned long long)byte << (8 * j);
                }
            }
            *(unsigned long long*)
                &Bs[n * 64 + slot_swz(n, oct >> 1) * 16 + (oct & 1) * 8] = v;
        }
    }

    // ---- stage A panel [128 m][64 k] i8 ----
    {
        const int m  = tid & 127;
        const int ob = tid >> 7;                // 0 or 1
        #pragma unroll 1
        for (int it = 0; it < 4; ++it) {
            const int oct = it * 2 + ob;
            const int k0  = oct * 8;
            unsigned long long v = 0ull;
            if (k0 < kg) {
                #pragma unroll
                for (int j = 0; j < 8; ++j) {
                    const int k = k0 + j;
                    unsigned byte = (k < kg) ? ((unsigned)ag[k * M_ + m0 + m] & 0xFFu) : 0u;
                    v |= (unsigned long long)byte << (8 * j);
                }
            }
            *(unsigned long long*)
                &As[m * 64 + slot_swz(m, oct >> 1) * 16 + (oct & 1) * 8] = v;
        }
    }

    // ---- stage scale row (8 KB) ----
    const float* scg = scale + (size_t)ind * N_;
    #pragma unroll
    for (int i = 0; i < 2; ++i) {
        const int o = i * 256 + tid;
        *(f32x4*)&ScL[o * 4] = *(const f32x4*)&scg[o * 4];
    }

    __syncthreads();        // single barrier

    // ---- compute + stream out ----
    // wave w owns m rows [w*32, w*32+32): two 16-row fragments (mf=0,1).
    // Per n-frag f (16 cols): one K=64 i8 MFMA per mf; store f32x4 along n.
    // Each of the wave's 32 rows receives a linear +64B walk over f ->
    // block writes a contiguous 1 MB span; L2 merges to full lines.
    const int wid  = tid >> 6;
    const int lane = tid & 63;
    const int l16  = lane & 15;
    const int lq   = lane >> 4;

    const int mr0 = wid * 32 + l16;     // local row, mf=0
    const int mr1 = mr0 + 16;           // local row, mf=1

    const i32x4 afr0 = *(const i32x4*)&As[mr0 * 64 + slot_swz(mr0, lq) * 16];
    const i32x4 afr1 = *(const i32x4*)&As[mr1 * 64 + slot_swz(mr1, lq) * 16];

    const float* ptg = pts + (size_t)ind * M_;
    const float pt0 = ptg[m0 + mr0];
    const float pt1 = ptg[m0 + mr1];

    float* orow0 = outg + (size_t)(m0 + mr0) * N_ + lq * 4;
    float* orow1 = outg + (size_t)(m0 + mr1) * N_ + lq * 4;

    const i32x4 zero = {0, 0, 0, 0};

    #pragma unroll 2
    for (int f = 0; f < 128; ++f) {
        const int n = f * 16 + l16;
        const i32x4 bf = *(const i32x4*)&Bs[n * 64 + slot_swz(n, lq) * 16];
        const f32x4 sc = *(const f32x4*)&ScL[f * 16 + lq * 4];

        // swapped operands: D = B_frag x A_frag -> lane holds
        // m = l16 (col of D), n = lq*4 + r -> f32x4 store along n. Exact i32.
        i32x4 d0 = __builtin_amdgcn_mfma_i32_16x16x64_i8(bf, afr0, zero, 0, 0, 0);
        i32x4 d1 = __builtin_amdgcn_mfma_i32_16x16x64_i8(bf, afr1, zero, 0, 0, 0);

        f32x4 v0, v1;
        #pragma unroll
        for (int r = 0; r < 4; ++r) {
            v0[r] = ((float)d0[r] * sc[r]) * pt0;   // same mul order as ref
            v1[r] = ((float)d1[r] * sc[r]) * pt1;
        }
        *(f32x4*)(orow0 + f * 16) = v0;
        *(f32x4*)(orow1 + f * 16) = v1;
    }
}

extern "C" void kernel_launch(void* const* d_in, const int* in_sizes, int n_in,
                              void* d_out, int out_size, void* d_ws, size_t ws_size,
                              hipStream_t stream) {
    const int*   a     = (const int*)d_in[0];
    const int*   b     = (const int*)d_in[1];
    const float* scale = (const float*)d_in[2];
    const float* pts   = (const float*)d_in[3];
    const int*   gl    = (const int*)d_in[4];
    float*       out   = (float*)d_out;

    dim3 grid(G_ * 16);     // 256 blocks: one contiguous 1 MB output chunk each
    dim3 block(256);
    grouped_gemm_kernel<<<grid, block, 0, stream>>>(a, b, scale, pts, gl, out);
}

// Round 9
// 69.516 us; speedup vs baseline: 3.7681x; 3.7681x over previous
//
#include <hip/hip_runtime.h>
#include <hip/hip_bf16.h>

// Grouped int32 GEMM, scaled, f32 out.
// A flat: per group [k, M] (k-major). B flat: per group [k, N].
// O[g][m][n] = (sum_k A[k][m]*B[k][n]) * scale[g][n] * pts[g][m]
// Values 0..127 -> exact in bf16; sums < 2^24 -> exact in f32 MFMA accum.
//
// Round 9 = round 6 (68.3us, exact, XCD-chunked) + 4 blocks/CU.
// r8's counters proved HBM traffic is already minimal (273MB total:
// FETCH 4.3MB + WRITE 268MB) -> the 70us family is RATE-limited, not
// traffic-limited (~4 TB/s effective vs 6.3 achievable). Theory: the
// stage->sync->MFMA->store chain leaves store drain / stage latency
// exposed with only 3 resident blocks/CU. 4 blocks/CU (LDS 4x36=144KB,
// VGPR<=128) adds overlap + store MLP + phase diversity.

#define M_ 2048
#define N_ 2048
#define G_ 16
#define BM 128
#define BN 128
#define KP 72   // LDS row stride in bf16 elems (144B, multiple of 16B for b128)
#define KT 64   // K tile (>= max group k)

typedef __attribute__((ext_vector_type(8))) short bf16x8;
typedef __attribute__((ext_vector_type(4))) float f32x4;
typedef __attribute__((ext_vector_type(4))) int   int4v;

// 8B-granule XOR swizzle within a row: spreads staging writes across banks.
// Applied identically on write and read (same involution both sides).
__device__ __forceinline__ int swz8(int row, int g) {
    return g ^ (((row >> 2) & 3) << 2);
}

// Stage one KT x 128 tile (src laid out [k, ld], cols col0..col0+127) into
// dst[m][k] bf16 with granule swizzle. 256 threads, each handles two 4k x 4m
// cells: 4 int4 loads -> register 4x4 transpose -> 4 ds_write_b64.
__device__ __forceinline__ void stage_tile_v(const int* __restrict__ srcg, int ld,
                                             int col0, int kg,
                                             unsigned short (*dst)[KP], int tid)
{
    #pragma unroll
    for (int cc = 0; cc < 2; ++cc) {
        const int c  = tid + cc * 256;
        const int mc = c & 31;          // m-cell 0..31
        const int kc = c >> 5;          // k-cell 0..15 (8B granule index)
        const int k0 = kc * 4;
        const int mm = mc * 4;

        if (k0 >= kg) {
            uint2 z = {0u, 0u};
            #pragma unroll
            for (int j = 0; j < 4; ++j) {
                int r = mm + j;
                *(uint2*)((char*)&dst[r][0] + swz8(r, kc) * 8) = z;
            }
        } else {
            int4v L[4];
            const int off = k0 * ld + col0 + mm;    // 32-bit element offset
            #pragma unroll
            for (int i = 0; i < 4; ++i) {
                L[i] = (k0 + i < kg) ? *(const int4v*)(srcg + off + i * ld)
                                     : (int4v){0, 0, 0, 0};
            }
            #pragma unroll
            for (int j = 0; j < 4; ++j) {
                // bf16 of L[0..3][j]: exact for 0..127
                unsigned u0 = __float_as_uint((float)L[0][j]);
                unsigned u1 = __float_as_uint((float)L[1][j]);
                unsigned u2 = __float_as_uint((float)L[2][j]);
                unsigned u3 = __float_as_uint((float)L[3][j]);
                uint2 w;
                w.x = (u0 >> 16) | (u1 & 0xFFFF0000u);
                w.y = (u2 >> 16) | (u3 & 0xFFFF0000u);
                int r = mm + j;
                *(uint2*)((char*)&dst[r][0] + swz8(r, kc) * 8) = w;
            }
        }
    }
}

__device__ __forceinline__ bf16x8 frag_read(const unsigned short (*s)[KP],
                                            int r, int gg)
{
    return *(const bf16x8*)((const char*)&s[r][0] + swz8(r, gg) * 8);
}

__global__ __launch_bounds__(256, 4)
void grouped_gemm_kernel(const int* __restrict__ a,
                         const int* __restrict__ b,
                         const float* __restrict__ scale,
                         const float* __restrict__ pts,
                         const int* __restrict__ gl,
                         float* __restrict__ out)
{
    __shared__ __align__(16) unsigned short As[BM][KP];
    __shared__ __align__(16) unsigned short Bs[BN][KP];

    const int tid = threadIdx.x;
    // XCD-chunked swizzle: launch order round-robins XCDs, so blocks with
    // bx0 % 8 == x land on XCD x. Give XCD x virtual tiles x*512..x*512+511
    // = 2 whole groups -> per-XCD input working set ~1MB, fits 4MB L2.
    const int bx0 = blockIdx.x;
    const int bx  = (bx0 & 7) * 512 + (bx0 >> 3);   // bijective: 4096 = 8*512
    const int ind = bx >> 8;        // 256 tiles per group (16x16)
    const int t   = bx & 255;
    const int m0  = (t >> 4) * BM;
    const int n0  = (t & 15) * BN;  // n fastest: 16 consecutive tiles share A-strip

    const int prefix = (ind == 0) ? 0 : gl[ind - 1];
    const int kg     = gl[ind] - prefix;

    float* outg = out + (size_t)ind * M_ * N_;

    if (kg <= 0) {
        // empty group: zero-fill this 128x128 tile (d_out is poisoned)
        f32x4 z = {0.f, 0.f, 0.f, 0.f};
        #pragma unroll
        for (int i = 0; i < 16; ++i) {
            int idx = i * 256 + tid;
            int r   = idx >> 5;
            int c   = (idx & 31) * 4;
            *(f32x4*)(outg + (size_t)(m0 + r) * N_ + n0 + c) = z;
        }
        return;
    }

    const int* ag = a + (size_t)prefix * M_;
    const int* bg = b + (size_t)prefix * N_;

    const int wid  = tid >> 6;      // 4 waves -> 2x2 sub-tiles of 64x64
    const int lane = tid & 63;
    const int wr   = wid >> 1;
    const int wc   = wid & 1;
    const int l16  = lane & 15;
    const int lq   = lane >> 4;

    f32x4 acc[4][4];
    #pragma unroll
    for (int i = 0; i < 4; ++i)
        #pragma unroll
        for (int j = 0; j < 4; ++j)
            acc[i][j] = (f32x4){0.f, 0.f, 0.f, 0.f};

    // single LDS fill: KT=64 covers every group's k (kg <= 64)
    stage_tile_v(ag, M_, m0, kg, As, tid);
    stage_tile_v(bg, N_, n0, kg, Bs, tid);
    __syncthreads();

    const int nk = (kg + 31) / 32;      // 1 or 2 K=32 MFMA steps
    for (int kf = 0; kf < nk; ++kf) {
        const int gg = kf * 8 + lq * 2; // k-granule pair for this fragment
        bf16x8 bfr[4];
        #pragma unroll
        for (int fn = 0; fn < 4; ++fn)
            bfr[fn] = frag_read(Bs, wc * 64 + fn * 16 + l16, gg);
        #pragma unroll
        for (int fm = 0; fm < 4; ++fm) {
            bf16x8 afr = frag_read(As, wr * 64 + fm * 16 + l16, gg);
            #pragma unroll
            for (int fn = 0; fn < 4; ++fn)
                // swapped operands: D = B_frag x A_frag -> lane holds
                // m = l16 (col), n = lq*4 + r -> f32x4 store along n
                acc[fm][fn] = __builtin_amdgcn_mfma_f32_16x16x32_bf16(
                    bfr[fn], afr, acc[fm][fn], 0, 0, 0);
        }
    }

    // epilogue: out = (acc * scale[n]) * pts[m]  (same mul order as reference)
    const float* scg = scale + (size_t)ind * N_;
    const float* ptg = pts + (size_t)ind * M_;

    f32x4 sc[4];
    #pragma unroll
    for (int fn = 0; fn < 4; ++fn)
        sc[fn] = *(const f32x4*)&scg[n0 + wc * 64 + fn * 16 + lq * 4];

    #pragma unroll
    for (int fm = 0; fm < 4; ++fm) {
        int m = m0 + wr * 64 + fm * 16 + l16;
        float pt = ptg[m];
        float* orow = outg + (size_t)m * N_ + n0 + wc * 64 + lq * 4;
        #pragma unroll
        for (int fn = 0; fn < 4; ++fn) {
            f32x4 v;
            #pragma unroll
            for (int r = 0; r < 4; ++r)
                v[r] = (acc[fm][fn][r] * sc[fn][r]) * pt;
            *(f32x4*)(orow + fn * 16) = v;
        }
    }
}

extern "C" void kernel_launch(void* const* d_in, const int* in_sizes, int n_in,
                              void* d_out, int out_size, void* d_ws, size_t ws_size,
                              hipStream_t stream) {
    const int*   a     = (const int*)d_in[0];
    const int*   b     = (const int*)d_in[1];
    const float* scale = (const float*)d_in[2];
    const float* pts   = (const float*)d_in[3];
    const int*   gl    = (const int*)d_in[4];
    float*       out   = (float*)d_out;

    dim3 grid(G_ * (M_ / BM) * (N_ / BN));   // 16 * 256 = 4096
    dim3 block(256);
    grouped_gemm_kernel<<<grid, block, 0, stream>>>(a, b, scale, pts, gl, out);
}

// Round 10
// 51.294 us; speedup vs baseline: 5.1066x; 1.3552x over previous
//
#include <hip/hip_runtime.h>
#include <hip/hip_bf16.h>

// Grouped int32 GEMM, scaled, f32 out.
// A flat: per group [k, M] (k-major). B flat: per group [k, N].
// O[g][m][n] = (sum_k A[k][m]*B[k][n]) * scale[g][n] * pts[g][m]
// Values 0..127 -> exact in bf16; sums < 2^24 -> exact in f32 MFMA accum.
//
// Round 10 = r6 (68.3us: XCD-chunked, exact) + r5 C-bounce epilogue +
// NON-TEMPORAL stream-out. Model: allocating stores reach DRAM in L2
// EVICTION order (set/way-scrambled) -> ~4 TB/s page efficiency; the
// 7 TB/s fill achieves page-sequential arrivals. nt bypasses L2, but r4
// showed nt with 64B scattered segments = partial lines = RMW = worse.
// The untested cell: nt stores whose per-instruction segments are
// full-line contiguous (C-bounce gives 512B/instr, linear row order)
// -> write-combine to full lines, arrive in issue order -> page-friendly.

#define M_ 2048
#define N_ 2048
#define G_ 16
#define BM 128
#define BN 128
#define KP 72    // LDS row stride in bf16 elems (144B, multiple of 16B)
#define KT 64    // K tile (>= max group k)
#define CP 132   // C-bounce row stride in floats (528B, 16B-multiple, bank-skewed)

typedef __attribute__((ext_vector_type(8))) short bf16x8;
typedef __attribute__((ext_vector_type(4))) float f32x4;
typedef __attribute__((ext_vector_type(4))) int   int4v;

// 8B-granule XOR swizzle within a row: spreads staging writes across banks.
// Applied identically on write and read (same involution both sides).
__device__ __forceinline__ int swz8(int row, int g) {
    return g ^ (((row >> 2) & 3) << 2);
}

union LdsU {
    struct {
        unsigned short As[BM][KP];
        unsigned short Bs[BN][KP];
    } ab;                         // 36 KB, live: stage + MFMA
    float Cs[BM][CP];             // 66 KB, live: epilogue bounce
};

// Stage one KT x 128 tile (src laid out [k, ld], cols col0..col0+127) into
// dst[m][k] bf16 with granule swizzle. 256 threads, each handles two 4k x 4m
// cells: 4 int4 loads -> register 4x4 transpose -> 4 ds_write_b64.
__device__ __forceinline__ void stage_tile_v(const int* __restrict__ srcg, int ld,
                                             int col0, int kg,
                                             unsigned short (*dst)[KP], int tid)
{
    #pragma unroll
    for (int cc = 0; cc < 2; ++cc) {
        const int c  = tid + cc * 256;
        const int mc = c & 31;          // m-cell 0..31
        const int kc = c >> 5;          // k-cell 0..15 (8B granule index)
        const int k0 = kc * 4;
        const int mm = mc * 4;

        if (k0 >= kg) {
            uint2 z = {0u, 0u};
            #pragma unroll
            for (int j = 0; j < 4; ++j) {
                int r = mm + j;
                *(uint2*)((char*)&dst[r][0] + swz8(r, kc) * 8) = z;
            }
        } else {
            int4v L[4];
            const int off = k0 * ld + col0 + mm;    // 32-bit element offset
            #pragma unroll
            for (int i = 0; i < 4; ++i) {
                L[i] = (k0 + i < kg) ? *(const int4v*)(srcg + off + i * ld)
                                     : (int4v){0, 0, 0, 0};
            }
            #pragma unroll
            for (int j = 0; j < 4; ++j) {
                // bf16 of L[0..3][j]: exact for 0..127
                unsigned u0 = __float_as_uint((float)L[0][j]);
                unsigned u1 = __float_as_uint((float)L[1][j]);
                unsigned u2 = __float_as_uint((float)L[2][j]);
                unsigned u3 = __float_as_uint((float)L[3][j]);
                uint2 w;
                w.x = (u0 >> 16) | (u1 & 0xFFFF0000u);
                w.y = (u2 >> 16) | (u3 & 0xFFFF0000u);
                int r = mm + j;
                *(uint2*)((char*)&dst[r][0] + swz8(r, kc) * 8) = w;
            }
        }
    }
}

__device__ __forceinline__ bf16x8 frag_read(const unsigned short (*s)[KP],
                                            int r, int gg)
{
    return *(const bf16x8*)((const char*)&s[r][0] + swz8(r, gg) * 8);
}

__global__ __launch_bounds__(256, 2)
void grouped_gemm_kernel(const int* __restrict__ a,
                         const int* __restrict__ b,
                         const float* __restrict__ scale,
                         const float* __restrict__ pts,
                         const int* __restrict__ gl,
                         float* __restrict__ out)
{
    __shared__ __align__(16) LdsU lds;

    const int tid = threadIdx.x;
    // XCD-chunked swizzle (bijective: 4096 = 8*512): XCD x gets 512
    // consecutive virtual tiles = 2 whole groups -> inputs L2-resident.
    const int bx0 = blockIdx.x;
    const int bx  = (bx0 & 7) * 512 + (bx0 >> 3);
    const int ind = bx >> 8;        // 256 tiles per group (16x16)
    const int t   = bx & 255;
    const int m0  = (t >> 4) * BM;
    const int n0  = (t & 15) * BN;  // n fastest: 16 consecutive tiles share A-strip

    const int prefix = (ind == 0) ? 0 : gl[ind - 1];
    const int kg     = gl[ind] - prefix;

    float* outg = out + (size_t)ind * M_ * N_;

    if (kg <= 0) {
        // empty group: zero-fill, 2 rows x 512B contiguous per wave-instr, nt
        f32x4 z = {0.f, 0.f, 0.f, 0.f};
        #pragma unroll
        for (int i = 0; i < 16; ++i) {
            int idx = i * 256 + tid;
            int r   = idx >> 5;
            int c   = (idx & 31) * 4;
            __builtin_nontemporal_store(
                z, (f32x4*)(outg + (size_t)(m0 + r) * N_ + n0 + c));
        }
        return;
    }

    const int* ag = a + (size_t)prefix * M_;
    const int* bg = b + (size_t)prefix * N_;

    const int wid  = tid >> 6;      // 4 waves -> 2x2 sub-tiles of 64x64
    const int lane = tid & 63;
    const int wr   = wid >> 1;
    const int wc   = wid & 1;
    const int l16  = lane & 15;
    const int lq   = lane >> 4;

    f32x4 acc[4][4];
    #pragma unroll
    for (int i = 0; i < 4; ++i)
        #pragma unroll
        for (int j = 0; j < 4; ++j)
            acc[i][j] = (f32x4){0.f, 0.f, 0.f, 0.f};

    // single LDS fill: KT=64 covers every group's k (kg <= 64)
    stage_tile_v(ag, M_, m0, kg, lds.ab.As, tid);
    stage_tile_v(bg, N_, n0, kg, lds.ab.Bs, tid);
    __syncthreads();

    const int nk = (kg + 31) / 32;      // 1 or 2 K=32 MFMA steps
    for (int kf = 0; kf < nk; ++kf) {
        const int gg = kf * 8 + lq * 2; // k-granule pair for this fragment
        bf16x8 bfr[4];
        #pragma unroll
        for (int fn = 0; fn < 4; ++fn)
            bfr[fn] = frag_read(lds.ab.Bs, wc * 64 + fn * 16 + l16, gg);
        #pragma unroll
        for (int fm = 0; fm < 4; ++fm) {
            bf16x8 afr = frag_read(lds.ab.As, wr * 64 + fm * 16 + l16, gg);
            #pragma unroll
            for (int fn = 0; fn < 4; ++fn)
                // swapped operands: D = B_frag x A_frag -> lane holds
                // m = l16 (col), n = lq*4 + r -> f32x4 along n
                acc[fm][fn] = __builtin_amdgcn_mfma_f32_16x16x32_bf16(
                    bfr[fn], afr, acc[fm][fn], 0, 0, 0);
        }
    }

    // scale: out = (acc * scale[n]) * pts[m]  (same mul order as reference)
    const float* scg = scale + (size_t)ind * N_;
    const float* ptg = pts + (size_t)ind * M_;

    f32x4 sc[4];
    #pragma unroll
    for (int fn = 0; fn < 4; ++fn)
        sc[fn] = *(const f32x4*)&scg[n0 + wc * 64 + fn * 16 + lq * 4];

    __syncthreads();                    // all frag reads done; safe to reuse LDS

    #pragma unroll
    for (int fm = 0; fm < 4; ++fm) {
        int mloc = wr * 64 + fm * 16 + l16;
        float pt = ptg[m0 + mloc];
        #pragma unroll
        for (int fn = 0; fn < 4; ++fn) {
            f32x4 v;
            #pragma unroll
            for (int r = 0; r < 4; ++r)
                v[r] = (acc[fm][fn][r] * sc[fn][r]) * pt;
            *(f32x4*)&lds.Cs[mloc][wc * 64 + fn * 16 + lq * 4] = v;
        }
    }

    __syncthreads();                    // C tile complete in LDS

    // stream out NON-TEMPORALLY: per wave-instr, 64 lanes cover 2 rows x
    // 512B contiguous (full 128B lines -> write-combine, no partial-line
    // RMW), rows emitted in linear order -> DRAM sees page-sequential runs.
    #pragma unroll
    for (int i = 0; i < 16; ++i) {
        int idx = i * 256 + tid;
        int r   = idx >> 5;             // 0..127
        int c   = (idx & 31) * 4;       // 0..124
        f32x4 v = *(const f32x4*)&lds.Cs[r][c];
        __builtin_nontemporal_store(
            v, (f32x4*)(outg + (size_t)(m0 + r) * N_ + n0 + c));
    }
}

extern "C" void kernel_launch(void* const* d_in, const int* in_sizes, int n_in,
                              void* d_out, int out_size, void* d_ws, size_t ws_size,
                              hipStream_t stream) {
    const int*   a     = (const int*)d_in[0];
    const int*   b     = (const int*)d_in[1];
    const float* scale = (const float*)d_in[2];
    const float* pts   = (const float*)d_in[3];
    const int*   gl    = (const int*)d_in[4];
    float*       out   = (float*)d_out;

    dim3 grid(G_ * (M_ / BM) * (N_ / BN));   // 16 * 256 = 4096
    dim3 block(256);
    grouped_gemm_kernel<<<grid, block, 0, stream>>>(a, b, scale, pts, gl, out);
}

// Round 11
// 50.719 us; speedup vs baseline: 5.1645x; 1.0113x over previous
//
#include <hip/hip_runtime.h>
#include <hip/hip_bf16.h>

// Grouped int32 GEMM, scaled, f32 out.
// A flat: per group [k, M] (k-major). B flat: per group [k, N].
// O[g][m][n] = (sum_k A[k][m]*B[k][n]) * scale[g][n] * pts[g][m]
// Values 0..127 -> exact in bf16; sums < 2^24 -> exact in f32 MFMA accum.
//
// Round 11 = round 10 (51.3us: nt + full-line C-bounce) with a HALF-TILE
// bounce buffer. Cs[64][132] = 33.8KB -> LDS union 36KB -> 4 blocks/CU
// (was 2 at 66KB). Stores are now nt (bypass L2, page-sequential); the
// remaining ~8us over the 43us floor is stage+MFMA+bounce critical path
// exposed behind only 1 neighbor block's store stream. 4 resident blocks
// per CU doubles the overlap pool. Same numerics, same store shape.

#define M_ 2048
#define N_ 2048
#define G_ 16
#define BM 128
#define BN 128
#define KP 72    // LDS row stride in bf16 elems (144B, multiple of 16B)
#define KT 64    // K tile (>= max group k)
#define CP 132   // C-bounce row stride in floats (528B, 16B-multiple, bank-skewed)

typedef __attribute__((ext_vector_type(8))) short bf16x8;
typedef __attribute__((ext_vector_type(4))) float f32x4;
typedef __attribute__((ext_vector_type(4))) int   int4v;

// 8B-granule XOR swizzle within a row: spreads staging writes across banks.
// Applied identically on write and read (same involution both sides).
__device__ __forceinline__ int swz8(int row, int g) {
    return g ^ (((row >> 2) & 3) << 2);
}

union LdsU {
    struct {
        unsigned short As[BM][KP];
        unsigned short Bs[BN][KP];
    } ab;                         // 36 KB, live: stage + MFMA
    float Cs[64][CP];             // 33.8 KB, live: epilogue bounce (half tile)
};

// Stage one KT x 128 tile (src laid out [k, ld], cols col0..col0+127) into
// dst[m][k] bf16 with granule swizzle. 256 threads, each handles two 4k x 4m
// cells: 4 int4 loads -> register 4x4 transpose -> 4 ds_write_b64.
__device__ __forceinline__ void stage_tile_v(const int* __restrict__ srcg, int ld,
                                             int col0, int kg,
                                             unsigned short (*dst)[KP], int tid)
{
    #pragma unroll
    for (int cc = 0; cc < 2; ++cc) {
        const int c  = tid + cc * 256;
        const int mc = c & 31;          // m-cell 0..31
        const int kc = c >> 5;          // k-cell 0..15 (8B granule index)
        const int k0 = kc * 4;
        const int mm = mc * 4;

        if (k0 >= kg) {
            uint2 z = {0u, 0u};
            #pragma unroll
            for (int j = 0; j < 4; ++j) {
                int r = mm + j;
                *(uint2*)((char*)&dst[r][0] + swz8(r, kc) * 8) = z;
            }
        } else {
            int4v L[4];
            const int off = k0 * ld + col0 + mm;    // 32-bit element offset
            #pragma unroll
            for (int i = 0; i < 4; ++i) {
                L[i] = (k0 + i < kg) ? *(const int4v*)(srcg + off + i * ld)
                                     : (int4v){0, 0, 0, 0};
            }
            #pragma unroll
            for (int j = 0; j < 4; ++j) {
                // bf16 of L[0..3][j]: exact for 0..127
                unsigned u0 = __float_as_uint((float)L[0][j]);
                unsigned u1 = __float_as_uint((float)L[1][j]);
                unsigned u2 = __float_as_uint((float)L[2][j]);
                unsigned u3 = __float_as_uint((float)L[3][j]);
                uint2 w;
                w.x = (u0 >> 16) | (u1 & 0xFFFF0000u);
                w.y = (u2 >> 16) | (u3 & 0xFFFF0000u);
                int r = mm + j;
                *(uint2*)((char*)&dst[r][0] + swz8(r, kc) * 8) = w;
            }
        }
    }
}

__device__ __forceinline__ bf16x8 frag_read(const unsigned short (*s)[KP],
                                            int r, int gg)
{
    return *(const bf16x8*)((const char*)&s[r][0] + swz8(r, gg) * 8);
}

__global__ __launch_bounds__(256, 4)
void grouped_gemm_kernel(const int* __restrict__ a,
                         const int* __restrict__ b,
                         const float* __restrict__ scale,
                         const float* __restrict__ pts,
                         const int* __restrict__ gl,
                         float* __restrict__ out)
{
    __shared__ __align__(16) LdsU lds;

    const int tid = threadIdx.x;
    // XCD-chunked swizzle (bijective: 4096 = 8*512): XCD x gets 512
    // consecutive virtual tiles = 2 whole groups -> inputs L2-resident.
    const int bx0 = blockIdx.x;
    const int bx  = (bx0 & 7) * 512 + (bx0 >> 3);
    const int ind = bx >> 8;        // 256 tiles per group (16x16)
    const int t   = bx & 255;
    const int m0  = (t >> 4) * BM;
    const int n0  = (t & 15) * BN;  // n fastest: 16 consecutive tiles share A-strip

    const int prefix = (ind == 0) ? 0 : gl[ind - 1];
    const int kg     = gl[ind] - prefix;

    float* outg = out + (size_t)ind * M_ * N_;

    if (kg <= 0) {
        // empty group: zero-fill, 2 rows x 512B contiguous per wave-instr, nt
        f32x4 z = {0.f, 0.f, 0.f, 0.f};
        #pragma unroll
        for (int i = 0; i < 16; ++i) {
            int idx = i * 256 + tid;
            int r   = idx >> 5;
            int c   = (idx & 31) * 4;
            __builtin_nontemporal_store(
                z, (f32x4*)(outg + (size_t)(m0 + r) * N_ + n0 + c));
        }
        return;
    }

    const int* ag = a + (size_t)prefix * M_;
    const int* bg = b + (size_t)prefix * N_;

    const int wid  = tid >> 6;      // 4 waves -> 2x2 sub-tiles of 64x64
    const int lane = tid & 63;
    const int wr   = wid >> 1;
    const int wc   = wid & 1;
    const int l16  = lane & 15;
    const int lq   = lane >> 4;

    f32x4 acc[4][4];
    #pragma unroll
    for (int i = 0; i < 4; ++i)
        #pragma unroll
        for (int j = 0; j < 4; ++j)
            acc[i][j] = (f32x4){0.f, 0.f, 0.f, 0.f};

    // single LDS fill: KT=64 covers every group's k (kg <= 64)
    stage_tile_v(ag, M_, m0, kg, lds.ab.As, tid);
    stage_tile_v(bg, N_, n0, kg, lds.ab.Bs, tid);
    __syncthreads();

    const int nk = (kg + 31) / 32;      // 1 or 2 K=32 MFMA steps
    for (int kf = 0; kf < nk; ++kf) {
        const int gg = kf * 8 + lq * 2; // k-granule pair for this fragment
        bf16x8 bfr[4];
        #pragma unroll
        for (int fn = 0; fn < 4; ++fn)
            bfr[fn] = frag_read(lds.ab.Bs, wc * 64 + fn * 16 + l16, gg);
        #pragma unroll
        for (int fm = 0; fm < 4; ++fm) {
            bf16x8 afr = frag_read(lds.ab.As, wr * 64 + fm * 16 + l16, gg);
            #pragma unroll
            for (int fn = 0; fn < 4; ++fn)
                // swapped operands: D = B_frag x A_frag -> lane holds
                // m = l16 (col), n = lq*4 + r -> f32x4 along n
                acc[fm][fn] = __builtin_amdgcn_mfma_f32_16x16x32_bf16(
                    bfr[fn], afr, acc[fm][fn], 0, 0, 0);
        }
    }

    // scale: out = (acc * scale[n]) * pts[m]  (same mul order as reference)
    const float* scg = scale + (size_t)ind * N_;
    const float* ptg = pts + (size_t)ind * M_;

    f32x4 sc[4];
    #pragma unroll
    for (int fn = 0; fn < 4; ++fn)
        sc[fn] = *(const f32x4*)&scg[n0 + wc * 64 + fn * 16 + lq * 4];

    // Half-tile bounce: rows 0..63 live in waves with wr==0, rows 64..127
    // in wr==1. Two deposit+stream phases through a 64-row buffer.
    #pragma unroll
    for (int half = 0; half < 2; ++half) {
        __syncthreads();                // frag reads (h0) / prev stream (h1) done
        if (wr == half) {
            #pragma unroll
            for (int fm = 0; fm < 4; ++fm) {
                int rloc = fm * 16 + l16;           // 0..63 within half
                float pt = ptg[m0 + half * 64 + rloc];
                #pragma unroll
                for (int fn = 0; fn < 4; ++fn) {
                    f32x4 v;
                    #pragma unroll
                    for (int r = 0; r < 4; ++r)
                        v[r] = (acc[fm][fn][r] * sc[fn][r]) * pt;
                    *(f32x4*)&lds.Cs[rloc][wc * 64 + fn * 16 + lq * 4] = v;
                }
            }
        }
        __syncthreads();                // half-tile complete in LDS

        // stream out nt: 64 lanes cover 2 rows x 512B contiguous per instr,
        // full 128B lines, rows in linear order -> page-sequential arrivals.
        #pragma unroll
        for (int i = 0; i < 8; ++i) {
            int idx = i * 256 + tid;
            int r   = idx >> 5;         // 0..63 within half
            int c   = (idx & 31) * 4;   // 0..124
            f32x4 v = *(const f32x4*)&lds.Cs[r][c];
            __builtin_nontemporal_store(
                v, (f32x4*)(outg + (size_t)(m0 + half * 64 + r) * N_ + n0 + c));
        }
    }
}

extern "C" void kernel_launch(void* const* d_in, const int* in_sizes, int n_in,
                              void* d_out, int out_size, void* d_ws, size_t ws_size,
                              hipStream_t stream) {
    const int*   a     = (const int*)d_in[0];
    const int*   b     = (const int*)d_in[1];
    const float* scale = (const float*)d_in[2];
    const float* pts   = (const float*)d_in[3];
    const int*   gl    = (const int*)d_in[4];
    float*       out   = (float*)d_out;

    dim3 grid(G_ * (M_ / BM) * (N_ / BN));   // 16 * 256 = 4096
    dim3 block(256);
    grouped_gemm_kernel<<<grid, block, 0, stream>>>(a, b, scale, pts, gl, out);
}